// Round 1
// baseline (15170.341 us; speedup 1.0000x reference)
//
#include <hip/hip_runtime.h>
#include <math.h>

#define SLEN 64
#define BATCH 256
#define VIND 128
#define VOUTD 128
#define UDIM 1024
#define EDIM 512
#define TDEC 25

// ---------------------------------------------------------------------------
// init: zero h0, write output row 0 (start one-hot), idx=START_CODE(0)
// ---------------------------------------------------------------------------
__global__ void init_kernel(float* __restrict__ h0, float* __restrict__ out0,
                            int* __restrict__ idx) {
    int i = blockIdx.x * blockDim.x + threadIdx.x;
    if (i < BATCH * UDIM) h0[i] = 0.0f;
    if (i < BATCH * VOUTD) out0[i] = ((i & (VOUTD - 1)) == 0) ? 1.0f : 0.0f;
    if (i < BATCH) idx[i] = 0;
}

// ---------------------------------------------------------------------------
// Generic C[M,N] = A[M,K] @ W[N,K]^T + bias[N]   (all dims multiples of 32)
// 32x32 tile, 256 threads (16x16), 2x2 micro-tile
// ---------------------------------------------------------------------------
__global__ __launch_bounds__(256) void gemm_bias_nt(
    const float* __restrict__ A, const float* __restrict__ W,
    const float* __restrict__ bias, float* __restrict__ C,
    int M, int N, int K) {
    __shared__ float sA[32][33];  // [k][m]
    __shared__ float sW[32][33];  // [k][n]
    int tx = threadIdx.x, ty = threadIdx.y;
    int tid = ty * 16 + tx;
    int lr = tid >> 5, lc = tid & 31;
    int m0 = blockIdx.y * 32, n0 = blockIdx.x * 32;
    float acc00 = 0.f, acc01 = 0.f, acc10 = 0.f, acc11 = 0.f;

    for (int k0 = 0; k0 < K; k0 += 32) {
#pragma unroll
        for (int i = 0; i < 4; i++) {
            int row = lr + 8 * i;
            sA[lc][row] = A[(size_t)(m0 + row) * K + k0 + lc];
            sW[lc][row] = W[(size_t)(n0 + row) * K + k0 + lc];
        }
        __syncthreads();
#pragma unroll
        for (int k = 0; k < 32; k++) {
            float a0 = sA[k][2 * ty], a1 = sA[k][2 * ty + 1];
            float b0 = sW[k][2 * tx], b1 = sW[k][2 * tx + 1];
            acc00 += a0 * b0; acc01 += a0 * b1;
            acc10 += a1 * b0; acc11 += a1 * b1;
        }
        __syncthreads();
    }
    float bn0 = bias ? bias[n0 + 2 * tx] : 0.f;
    float bn1 = bias ? bias[n0 + 2 * tx + 1] : 0.f;
    size_t r0 = (size_t)(m0 + 2 * ty) * N + n0 + 2 * tx;
    size_t r1 = (size_t)(m0 + 2 * ty + 1) * N + n0 + 2 * tx;
    C[r0] = acc00 + bn0;
    C[r0 + 1] = acc01 + bn1;
    C[r1] = acc10 + bn0;
    C[r1 + 1] = acc11 + bn1;
}

// ---------------------------------------------------------------------------
// Fused GRU step. For output tile [m0:m0+32, u0:u0+32] of h:
//   acc_r = Aih@Wih_r^T + h@Whh_r^T ; acc_z likewise
//   acc_in = Aih@Wih_n^T (ih only) ; acc_hn = h@Whh_n^T (hh only)
//   r=sig(acc_r + bih_r + bhh_r); z=sig(...); n=tanh(acc_in+bih_n + r*(acc_hn+bhh_n))
//   h' = (1-z)*n + z*h ; optional encoder masking + enc_out write
// ---------------------------------------------------------------------------
__global__ __launch_bounds__(256) void gru_step_kernel(
    const float* __restrict__ Aih, int Kih,
    const float* __restrict__ Wih, const float* __restrict__ bih,
    const float* __restrict__ hin,
    const float* __restrict__ Whh, const float* __restrict__ bhh,
    float* __restrict__ hout, float* __restrict__ enc_out,
    const int* __restrict__ x_len, int t) {
    __shared__ float sA[32][33];
    __shared__ float sW[3][32][33];
    int tx = threadIdx.x, ty = threadIdx.y;
    int tid = ty * 16 + tx;
    int lr = tid >> 5, lc = tid & 31;
    int m0 = blockIdx.y * 32, u0 = blockIdx.x * 32;

    float ar[2][2] = {{0.f, 0.f}, {0.f, 0.f}};
    float az[2][2] = {{0.f, 0.f}, {0.f, 0.f}};
    float ai[2][2] = {{0.f, 0.f}, {0.f, 0.f}};
    float ah[2][2] = {{0.f, 0.f}, {0.f, 0.f}};

    // ---- hh phase: K = UDIM over hin @ Whh^T ----
    for (int k0 = 0; k0 < UDIM; k0 += 32) {
#pragma unroll
        for (int i = 0; i < 4; i++) {
            int row = lr + 8 * i;
            sA[lc][row] = hin[(size_t)(m0 + row) * UDIM + k0 + lc];
            sW[0][lc][row] = Whh[(size_t)(u0 + row) * UDIM + k0 + lc];
            sW[1][lc][row] = Whh[(size_t)(UDIM + u0 + row) * UDIM + k0 + lc];
            sW[2][lc][row] = Whh[(size_t)(2 * UDIM + u0 + row) * UDIM + k0 + lc];
        }
        __syncthreads();
#pragma unroll
        for (int k = 0; k < 32; k++) {
            float a0 = sA[k][2 * ty], a1 = sA[k][2 * ty + 1];
            float r0 = sW[0][k][2 * tx], r1 = sW[0][k][2 * tx + 1];
            float z0 = sW[1][k][2 * tx], z1 = sW[1][k][2 * tx + 1];
            float n0 = sW[2][k][2 * tx], n1 = sW[2][k][2 * tx + 1];
            ar[0][0] += a0 * r0; ar[0][1] += a0 * r1; ar[1][0] += a1 * r0; ar[1][1] += a1 * r1;
            az[0][0] += a0 * z0; az[0][1] += a0 * z1; az[1][0] += a1 * z0; az[1][1] += a1 * z1;
            ah[0][0] += a0 * n0; ah[0][1] += a0 * n1; ah[1][0] += a1 * n0; ah[1][1] += a1 * n1;
        }
        __syncthreads();
    }
    // ---- ih phase: K = Kih over Aih @ Wih^T ----
    for (int k0 = 0; k0 < Kih; k0 += 32) {
#pragma unroll
        for (int i = 0; i < 4; i++) {
            int row = lr + 8 * i;
            sA[lc][row] = Aih[(size_t)(m0 + row) * Kih + k0 + lc];
            sW[0][lc][row] = Wih[(size_t)(u0 + row) * Kih + k0 + lc];
            sW[1][lc][row] = Wih[(size_t)(UDIM + u0 + row) * Kih + k0 + lc];
            sW[2][lc][row] = Wih[(size_t)(2 * UDIM + u0 + row) * Kih + k0 + lc];
        }
        __syncthreads();
#pragma unroll
        for (int k = 0; k < 32; k++) {
            float a0 = sA[k][2 * ty], a1 = sA[k][2 * ty + 1];
            float r0 = sW[0][k][2 * tx], r1 = sW[0][k][2 * tx + 1];
            float z0 = sW[1][k][2 * tx], z1 = sW[1][k][2 * tx + 1];
            float n0 = sW[2][k][2 * tx], n1 = sW[2][k][2 * tx + 1];
            ar[0][0] += a0 * r0; ar[0][1] += a0 * r1; ar[1][0] += a1 * r0; ar[1][1] += a1 * r1;
            az[0][0] += a0 * z0; az[0][1] += a0 * z1; az[1][0] += a1 * z0; az[1][1] += a1 * z1;
            ai[0][0] += a0 * n0; ai[0][1] += a0 * n1; ai[1][0] += a1 * n0; ai[1][1] += a1 * n1;
        }
        __syncthreads();
    }
    // ---- epilogue ----
#pragma unroll
    for (int i = 0; i < 2; i++) {
#pragma unroll
        for (int j = 0; j < 2; j++) {
            int m = m0 + 2 * ty + i;
            int u = u0 + 2 * tx + j;
            float sr = ar[i][j] + bih[u] + bhh[u];
            float sz = az[i][j] + bih[UDIM + u] + bhh[UDIM + u];
            float rg = 1.f / (1.f + expf(-sr));
            float zg = 1.f / (1.f + expf(-sz));
            float nn = tanhf(ai[i][j] + bih[2 * UDIM + u] + rg * (ah[i][j] + bhh[2 * UDIM + u]));
            float hp = hin[(size_t)m * UDIM + u];
            float hv = (1.f - zg) * nn + zg * hp;
            if (x_len) {
                bool msk = t < x_len[m];
                hout[(size_t)m * UDIM + u] = msk ? hv : hp;
                enc_out[((size_t)m * SLEN + t) * UDIM + u] = msk ? hv : 0.f;
            } else {
                hout[(size_t)m * UDIM + u] = hv;
            }
        }
    }
}

// ---------------------------------------------------------------------------
// Attention + context + emb-gather → gx[b, 0:U]=ctx, gx[b, U:U+E]=emb
// One block per batch element, 256 threads (4 waves).
// ---------------------------------------------------------------------------
__global__ __launch_bounds__(256) void attn_ctx_kernel(
    const float* __restrict__ enc_proj, const float* __restrict__ enc_out,
    const float* __restrict__ tmp2, const float* __restrict__ V_W,
    const float* __restrict__ V_b,
    const float* __restrict__ o2h_W, const float* __restrict__ o2h_b,
    const int* __restrict__ idx, float* __restrict__ gx) {
    int b = blockIdx.x;
    int tid = threadIdx.x;
    int lane = tid & 63, wave = tid >> 6;
    __shared__ float s_t2[UDIM];
    __shared__ float s_attn[SLEN];

    for (int u = tid; u < UDIM; u += 256) s_t2[u] = tmp2[(size_t)b * UDIM + u];
    __syncthreads();

    for (int s = wave; s < SLEN; s += 4) {
        const float* ep = enc_proj + ((size_t)b * SLEN + s) * UDIM;
        float p = 0.f;
        for (int u = lane; u < UDIM; u += 64)
            p += tanhf(ep[u] + s_t2[u]) * V_W[u];
#pragma unroll
        for (int off = 32; off > 0; off >>= 1) p += __shfl_xor(p, off);
        if (lane == 0) s_attn[s] = p + V_b[0];
    }
    __syncthreads();

    if (tid < 64) {
        float v = s_attn[tid];
        float mx = v;
#pragma unroll
        for (int off = 32; off > 0; off >>= 1) mx = fmaxf(mx, __shfl_xor(mx, off));
        float e = expf(v - mx);
        float sum = e;
#pragma unroll
        for (int off = 32; off > 0; off >>= 1) sum += __shfl_xor(sum, off);
        s_attn[tid] = e / sum;
    }
    __syncthreads();

    // ctx
    for (int u = tid; u < UDIM; u += 256) {
        float acc = 0.f;
#pragma unroll 8
        for (int s = 0; s < SLEN; s++)
            acc += s_attn[s] * enc_out[((size_t)b * SLEN + s) * UDIM + u];
        gx[(size_t)b * (UDIM + EDIM) + u] = acc;
    }
    // emb = o2h_W[:, idx[b]] + o2h_b
    int ib = idx[b];
    for (int e = tid; e < EDIM; e += 256)
        gx[(size_t)b * (UDIM + EDIM) + UDIM + e] = o2h_W[(size_t)e * VOUTD + ib] + o2h_b[e];
}

// ---------------------------------------------------------------------------
// argmax over VOUT=128 per batch row (first-max wins, as jnp.argmax)
// ---------------------------------------------------------------------------
__global__ void argmax_kernel(const float* __restrict__ pred, int* __restrict__ idx) {
    int b = blockIdx.x;
    int lane = threadIdx.x;  // 64 threads
    float v0 = pred[(size_t)b * VOUTD + lane];
    float v1 = pred[(size_t)b * VOUTD + 64 + lane];
    float v; int i;
    if (v1 > v0) { v = v1; i = lane + 64; } else { v = v0; i = lane; }
#pragma unroll
    for (int off = 32; off > 0; off >>= 1) {
        float ov = __shfl_xor(v, off);
        int oi = __shfl_xor(i, off);
        if (ov > v || (ov == v && oi < i)) { v = ov; i = oi; }
    }
    if (lane == 0) idx[b] = i;
}

// ---------------------------------------------------------------------------
extern "C" void kernel_launch(void* const* d_in, const int* in_sizes, int n_in,
                              void* d_out, int out_size, void* d_ws, size_t ws_size,
                              hipStream_t stream) {
    const float* x       = (const float*)d_in[0];   // [S,B,VIN]
    const int*   x_len   = (const int*)d_in[1];     // [B]
    const float* enc_Wih = (const float*)d_in[2];
    const float* enc_Whh = (const float*)d_in[3];
    const float* enc_bih = (const float*)d_in[4];
    const float* enc_bhh = (const float*)d_in[5];
    const float* dec_Wih = (const float*)d_in[6];
    const float* dec_Whh = (const float*)d_in[7];
    const float* dec_bih = (const float*)d_in[8];
    const float* dec_bhh = (const float*)d_in[9];
    const float* o2h_W   = (const float*)d_in[10];
    const float* o2h_b   = (const float*)d_in[11];
    const float* fc_W    = (const float*)d_in[12];
    const float* fc_b    = (const float*)d_in[13];
    const float* W1_W    = (const float*)d_in[14];
    const float* W1_b    = (const float*)d_in[15];
    const float* W2_W    = (const float*)d_in[16];
    const float* W2_b    = (const float*)d_in[17];
    const float* V_W     = (const float*)d_in[18];
    const float* V_b     = (const float*)d_in[19];
    float* out = (float*)d_out;

    float* ws = (float*)d_ws;
    float* hA       = ws;                          // B*U
    float* hB       = hA + (size_t)BATCH * UDIM;   // B*U
    float* enc_out  = hB + (size_t)BATCH * UDIM;   // B*S*U
    float* enc_proj = enc_out + (size_t)BATCH * SLEN * UDIM;  // B*S*U
    float* tmp2     = enc_proj + (size_t)BATCH * SLEN * UDIM; // B*U
    float* gx       = tmp2 + (size_t)BATCH * UDIM;            // B*(U+E)
    int*   idx      = (int*)(gx + (size_t)BATCH * (UDIM + EDIM));

    dim3 thr(16, 16);

    init_kernel<<<(BATCH * UDIM + 255) / 256, 256, 0, stream>>>(hA, out, idx);

    // ---- Encoder: 64 fused GRU steps ----
    float* hc = hA;
    float* hn = hB;
    for (int t = 0; t < SLEN; t++) {
        gru_step_kernel<<<dim3(UDIM / 32, BATCH / 32), thr, 0, stream>>>(
            x + (size_t)t * BATCH * VIND, VIND, enc_Wih, enc_bih,
            hc, enc_Whh, enc_bhh, hn, enc_out, x_len, t);
        float* tmp = hc; hc = hn; hn = tmp;
    }

    // ---- enc_proj = enc_out @ W1^T + W1_b  ([B*S, U] @ [U,U]^T) ----
    gemm_bias_nt<<<dim3(UDIM / 32, (BATCH * SLEN) / 32), thr, 0, stream>>>(
        enc_out, W1_W, W1_b, enc_proj, BATCH * SLEN, UDIM, UDIM);

    // ---- Greedy decode: 24 steps ----
    for (int st = 0; st < TDEC - 1; st++) {
        // tmp2 = h @ W2^T + W2_b
        gemm_bias_nt<<<dim3(UDIM / 32, BATCH / 32), thr, 0, stream>>>(
            hc, W2_W, W2_b, tmp2, BATCH, UDIM, UDIM);
        // attention + ctx + emb → gx
        attn_ctx_kernel<<<BATCH, 256, 0, stream>>>(
            enc_proj, enc_out, tmp2, V_W, V_b, o2h_W, o2h_b, idx, gx);
        // decoder GRU step
        gru_step_kernel<<<dim3(UDIM / 32, BATCH / 32), thr, 0, stream>>>(
            gx, UDIM + EDIM, dec_Wih, dec_bih,
            hc, dec_Whh, dec_bhh, hn, nullptr, nullptr, 0);
        // pred = hn @ fc^T + fc_b → out row (1+st)
        gemm_bias_nt<<<dim3(VOUTD / 32, BATCH / 32), thr, 0, stream>>>(
            hn, fc_W, fc_b, out + (size_t)(1 + st) * BATCH * VOUTD, BATCH, VOUTD, UDIM);
        // argmax feedback
        argmax_kernel<<<BATCH, 64, 0, stream>>>(out + (size_t)(1 + st) * BATCH * VOUTD, idx);
        float* tmp = hc; hc = hn; hn = tmp;
    }
}

// Round 2
// 12573.112 us; speedup vs baseline: 1.2066x; 1.2066x over previous
//
#include <hip/hip_runtime.h>
#include <math.h>

#define SLEN 64
#define BATCH 256
#define VIND 128
#define VOUTD 128
#define UDIM 1024
#define EDIM 512
#define TDEC 25
#define GXW (UDIM + EDIM)
#define U3 (3 * UDIM)

__device__ __forceinline__ float sigm(float x) { return 1.f / (1.f + expf(-x)); }

// ---------------------------------------------------------------------------
__global__ void init_kernel(float* __restrict__ h0, float* __restrict__ out0,
                            int* __restrict__ idx) {
    int i = blockIdx.x * blockDim.x + threadIdx.x;
    if (i < BATCH * UDIM) h0[i] = 0.0f;
    if (i < BATCH * VOUTD) out0[i] = ((i & (VOUTD - 1)) == 0) ? 1.0f : 0.0f;
    if (i < BATCH) idx[i] = 0;
}

// ---------------------------------------------------------------------------
// gemm64: C[M,N] = A[M,K] @ W[N,K]^T (+bias). BM=BN=64, BK=32.
// 256 threads, 4x4 microtile, b128 LDS fragment reads.
// Requires M%64==0, N%64==0, K%32==0, lda/ldw/ldc%4==0.
// ---------------------------------------------------------------------------
__global__ __launch_bounds__(256) void gemm64(
    const float* __restrict__ A, int lda,
    const float* __restrict__ W, int ldw,
    const float* __restrict__ bias,
    float* __restrict__ C, int ldc, int K) {
    __shared__ float sA[32][64];
    __shared__ float sW[32][64];
    int tid = threadIdx.x;
    int tx = tid & 15, ty = tid >> 4;
    int row = tid & 63, kc = tid >> 6;  // staging: 64 rows x 8 k-cols
    int m0 = blockIdx.y * 64, n0 = blockIdx.x * 64;
    const float* Ap = A + (size_t)(m0 + row) * lda + 8 * kc;
    const float* Wp = W + (size_t)(n0 + row) * ldw + 8 * kc;
    float acc[4][4] = {};

    for (int k0 = 0; k0 < K; k0 += 32) {
        float4 a0 = *(const float4*)(Ap + k0);
        float4 a1 = *(const float4*)(Ap + k0 + 4);
        float4 w0 = *(const float4*)(Wp + k0);
        float4 w1 = *(const float4*)(Wp + k0 + 4);
        int kk = 8 * kc;
        sA[kk + 0][row] = a0.x; sA[kk + 1][row] = a0.y;
        sA[kk + 2][row] = a0.z; sA[kk + 3][row] = a0.w;
        sA[kk + 4][row] = a1.x; sA[kk + 5][row] = a1.y;
        sA[kk + 6][row] = a1.z; sA[kk + 7][row] = a1.w;
        sW[kk + 0][row] = w0.x; sW[kk + 1][row] = w0.y;
        sW[kk + 2][row] = w0.z; sW[kk + 3][row] = w0.w;
        sW[kk + 4][row] = w1.x; sW[kk + 5][row] = w1.y;
        sW[kk + 6][row] = w1.z; sW[kk + 7][row] = w1.w;
        __syncthreads();
#pragma unroll
        for (int k = 0; k < 32; k++) {
            float4 av = *(const float4*)&sA[k][4 * ty];
            float4 wv = *(const float4*)&sW[k][4 * tx];
            acc[0][0] += av.x * wv.x; acc[0][1] += av.x * wv.y;
            acc[0][2] += av.x * wv.z; acc[0][3] += av.x * wv.w;
            acc[1][0] += av.y * wv.x; acc[1][1] += av.y * wv.y;
            acc[1][2] += av.y * wv.z; acc[1][3] += av.y * wv.w;
            acc[2][0] += av.z * wv.x; acc[2][1] += av.z * wv.y;
            acc[2][2] += av.z * wv.z; acc[2][3] += av.z * wv.w;
            acc[3][0] += av.w * wv.x; acc[3][1] += av.w * wv.y;
            acc[3][2] += av.w * wv.z; acc[3][3] += av.w * wv.w;
        }
        __syncthreads();
    }
    float4 bv = make_float4(0.f, 0.f, 0.f, 0.f);
    if (bias) bv = *(const float4*)(bias + n0 + 4 * tx);
#pragma unroll
    for (int i = 0; i < 4; i++) {
        float4 o;
        o.x = acc[i][0] + bv.x; o.y = acc[i][1] + bv.y;
        o.z = acc[i][2] + bv.z; o.w = acc[i][3] + bv.w;
        *(float4*)(C + (size_t)(m0 + 4 * ty + i) * ldc + n0 + 4 * tx) = o;
    }
}

// ---------------------------------------------------------------------------
// gemm32: BM=32, BN=64 variant for skinny-M GEMMs (tmp2, fc pred).
// 256 threads, 2x4 microtile.
// ---------------------------------------------------------------------------
__global__ __launch_bounds__(256) void gemm32(
    const float* __restrict__ A, int lda,
    const float* __restrict__ W, int ldw,
    const float* __restrict__ bias,
    float* __restrict__ C, int ldc, int K) {
    __shared__ float sA[32][32];
    __shared__ float sW[32][64];
    int tid = threadIdx.x;
    int tx = tid & 15, ty = tid >> 4;
    int arow = tid & 31, akc = tid >> 5;  // 32 rows x 8 k-chunks of 4
    int wrow = tid & 63, wkc = tid >> 6;  // 64 rows x 4 k-chunks of 8
    int m0 = blockIdx.y * 32, n0 = blockIdx.x * 64;
    const float* Ap = A + (size_t)(m0 + arow) * lda + 4 * akc;
    const float* Wp = W + (size_t)(n0 + wrow) * ldw + 8 * wkc;
    float acc[2][4] = {};

    for (int k0 = 0; k0 < K; k0 += 32) {
        float4 a0 = *(const float4*)(Ap + k0);
        float4 w0 = *(const float4*)(Wp + k0);
        float4 w1 = *(const float4*)(Wp + k0 + 4);
        int ak = 4 * akc;
        sA[ak + 0][arow] = a0.x; sA[ak + 1][arow] = a0.y;
        sA[ak + 2][arow] = a0.z; sA[ak + 3][arow] = a0.w;
        int wk = 8 * wkc;
        sW[wk + 0][wrow] = w0.x; sW[wk + 1][wrow] = w0.y;
        sW[wk + 2][wrow] = w0.z; sW[wk + 3][wrow] = w0.w;
        sW[wk + 4][wrow] = w1.x; sW[wk + 5][wrow] = w1.y;
        sW[wk + 6][wrow] = w1.z; sW[wk + 7][wrow] = w1.w;
        __syncthreads();
#pragma unroll
        for (int k = 0; k < 32; k++) {
            float2 av = *(const float2*)&sA[k][2 * ty];
            float4 wv = *(const float4*)&sW[k][4 * tx];
            acc[0][0] += av.x * wv.x; acc[0][1] += av.x * wv.y;
            acc[0][2] += av.x * wv.z; acc[0][3] += av.x * wv.w;
            acc[1][0] += av.y * wv.x; acc[1][1] += av.y * wv.y;
            acc[1][2] += av.y * wv.z; acc[1][3] += av.y * wv.w;
        }
        __syncthreads();
    }
    float4 bv = make_float4(0.f, 0.f, 0.f, 0.f);
    if (bias) bv = *(const float4*)(bias + n0 + 4 * tx);
#pragma unroll
    for (int i = 0; i < 2; i++) {
        float4 o;
        o.x = acc[i][0] + bv.x; o.y = acc[i][1] + bv.y;
        o.z = acc[i][2] + bv.z; o.w = acc[i][3] + bv.w;
        *(float4*)(C + (size_t)(m0 + 2 * ty + i) * ldc + n0 + 4 * tx) = o;
    }
}

// ---------------------------------------------------------------------------
// GRU gate combine: reads GIH[B,3U], GHH[B,3U], hin; writes hout (+enc_out).
// One float4 of u per thread.
// ---------------------------------------------------------------------------
__global__ __launch_bounds__(256) void gru_gates(
    const float* __restrict__ GIH, const float* __restrict__ GHH,
    const float* __restrict__ bih, const float* __restrict__ bhh,
    const float* __restrict__ hin, float* __restrict__ hout,
    float* __restrict__ enc_out, const int* __restrict__ x_len, int t) {
    int gid = blockIdx.x * 256 + threadIdx.x;  // B*U/4 threads total
    int b = gid >> 8;
    int u = (gid & 255) * 4;
    const float* gi = GIH + (size_t)b * U3;
    const float* gh = GHH + (size_t)b * U3;
    float4 gr = *(const float4*)(gi + u);
    float4 gz = *(const float4*)(gi + UDIM + u);
    float4 gn = *(const float4*)(gi + 2 * UDIM + u);
    float4 hr = *(const float4*)(gh + u);
    float4 hz = *(const float4*)(gh + UDIM + u);
    float4 hnv = *(const float4*)(gh + 2 * UDIM + u);
    float4 bir = *(const float4*)(bih + u);
    float4 biz = *(const float4*)(bih + UDIM + u);
    float4 bin = *(const float4*)(bih + 2 * UDIM + u);
    float4 bhr = *(const float4*)(bhh + u);
    float4 bhz = *(const float4*)(bhh + UDIM + u);
    float4 bhn = *(const float4*)(bhh + 2 * UDIM + u);
    float4 hp = *(const float4*)(hin + (size_t)b * UDIM + u);

    float4 hv;
    {
        float r = sigm(gr.x + bir.x + hr.x + bhr.x);
        float z = sigm(gz.x + biz.x + hz.x + bhz.x);
        float n = tanhf(gn.x + bin.x + r * (hnv.x + bhn.x));
        hv.x = (1.f - z) * n + z * hp.x;
        r = sigm(gr.y + bir.y + hr.y + bhr.y);
        z = sigm(gz.y + biz.y + hz.y + bhz.y);
        n = tanhf(gn.y + bin.y + r * (hnv.y + bhn.y));
        hv.y = (1.f - z) * n + z * hp.y;
        r = sigm(gr.z + bir.z + hr.z + bhr.z);
        z = sigm(gz.z + biz.z + hz.z + bhz.z);
        n = tanhf(gn.z + bin.z + r * (hnv.z + bhn.z));
        hv.z = (1.f - z) * n + z * hp.z;
        r = sigm(gr.w + bir.w + hr.w + bhr.w);
        z = sigm(gz.w + biz.w + hz.w + bhz.w);
        n = tanhf(gn.w + bin.w + r * (hnv.w + bhn.w));
        hv.w = (1.f - z) * n + z * hp.w;
    }
    if (x_len) {
        bool msk = t < x_len[b];
        float4 ho, eo;
        ho.x = msk ? hv.x : hp.x; eo.x = msk ? hv.x : 0.f;
        ho.y = msk ? hv.y : hp.y; eo.y = msk ? hv.y : 0.f;
        ho.z = msk ? hv.z : hp.z; eo.z = msk ? hv.z : 0.f;
        ho.w = msk ? hv.w : hp.w; eo.w = msk ? hv.w : 0.f;
        *(float4*)(hout + (size_t)b * UDIM + u) = ho;
        *(float4*)(enc_out + ((size_t)b * SLEN + t) * UDIM + u) = eo;
    } else {
        *(float4*)(hout + (size_t)b * UDIM + u) = hv;
    }
}

// ---------------------------------------------------------------------------
// Attention + context + emb-gather → gx[b,0:U]=ctx, gx[b,U:U+E]=emb
// ---------------------------------------------------------------------------
__global__ __launch_bounds__(256) void attn_ctx_kernel(
    const float* __restrict__ enc_proj, const float* __restrict__ enc_out,
    const float* __restrict__ tmp2, const float* __restrict__ V_W,
    const float* __restrict__ V_b,
    const float* __restrict__ o2h_W, const float* __restrict__ o2h_b,
    const int* __restrict__ idx, float* __restrict__ gx) {
    int b = blockIdx.x;
    int tid = threadIdx.x;
    int lane = tid & 63, wave = tid >> 6;
    __shared__ float s_t2[UDIM];
    __shared__ float s_v[UDIM];
    __shared__ float s_attn[SLEN];

    for (int u = tid; u < UDIM; u += 256) {
        s_t2[u] = tmp2[(size_t)b * UDIM + u];
        s_v[u] = V_W[u];
    }
    __syncthreads();

    for (int s = wave; s < SLEN; s += 4) {
        const float4* ep4 = (const float4*)(enc_proj + ((size_t)b * SLEN + s) * UDIM);
        const float4* t24 = (const float4*)s_t2;
        const float4* v4 = (const float4*)s_v;
        float p = 0.f;
        for (int u4 = lane; u4 < UDIM / 4; u4 += 64) {
            float4 e = ep4[u4];
            float4 t2 = t24[u4];
            float4 vv = v4[u4];
            p += tanhf(e.x + t2.x) * vv.x + tanhf(e.y + t2.y) * vv.y +
                 tanhf(e.z + t2.z) * vv.z + tanhf(e.w + t2.w) * vv.w;
        }
#pragma unroll
        for (int off = 32; off > 0; off >>= 1) p += __shfl_xor(p, off);
        if (lane == 0) s_attn[s] = p + V_b[0];
    }
    __syncthreads();

    if (tid < 64) {
        float v = s_attn[tid];
        float mx = v;
#pragma unroll
        for (int off = 32; off > 0; off >>= 1) mx = fmaxf(mx, __shfl_xor(mx, off));
        float e = expf(v - mx);
        float sum = e;
#pragma unroll
        for (int off = 32; off > 0; off >>= 1) sum += __shfl_xor(sum, off);
        s_attn[tid] = e / sum;
    }
    __syncthreads();

    for (int u4 = tid; u4 < UDIM / 4; u4 += 256) {
        float4 acc = make_float4(0.f, 0.f, 0.f, 0.f);
        const float4* eo4 = (const float4*)(enc_out + (size_t)b * SLEN * UDIM);
#pragma unroll 8
        for (int s = 0; s < SLEN; s++) {
            float4 e = eo4[s * (UDIM / 4) + u4];
            float a = s_attn[s];
            acc.x += a * e.x; acc.y += a * e.y;
            acc.z += a * e.z; acc.w += a * e.w;
        }
        *(float4*)(gx + (size_t)b * GXW + 4 * u4) = acc;
    }
    int ib = idx[b];
    for (int e = tid; e < EDIM; e += 256)
        gx[(size_t)b * GXW + UDIM + e] = o2h_W[(size_t)e * VOUTD + ib] + o2h_b[e];
}

// ---------------------------------------------------------------------------
__global__ void argmax_kernel(const float* __restrict__ pred, int* __restrict__ idx) {
    int b = blockIdx.x;
    int lane = threadIdx.x;  // 64 threads
    float v0 = pred[(size_t)b * VOUTD + lane];
    float v1 = pred[(size_t)b * VOUTD + 64 + lane];
    float v; int i;
    if (v1 > v0) { v = v1; i = lane + 64; } else { v = v0; i = lane; }
#pragma unroll
    for (int off = 32; off > 0; off >>= 1) {
        float ov = __shfl_xor(v, off);
        int oi = __shfl_xor(i, off);
        if (ov > v || (ov == v && oi < i)) { v = ov; i = oi; }
    }
    if (lane == 0) idx[b] = i;
}

// ---------------------------------------------------------------------------
extern "C" void kernel_launch(void* const* d_in, const int* in_sizes, int n_in,
                              void* d_out, int out_size, void* d_ws, size_t ws_size,
                              hipStream_t stream) {
    const float* x       = (const float*)d_in[0];
    const int*   x_len   = (const int*)d_in[1];
    const float* enc_Wih = (const float*)d_in[2];
    const float* enc_Whh = (const float*)d_in[3];
    const float* enc_bih = (const float*)d_in[4];
    const float* enc_bhh = (const float*)d_in[5];
    const float* dec_Wih = (const float*)d_in[6];
    const float* dec_Whh = (const float*)d_in[7];
    const float* dec_bih = (const float*)d_in[8];
    const float* dec_bhh = (const float*)d_in[9];
    const float* o2h_W   = (const float*)d_in[10];
    const float* o2h_b   = (const float*)d_in[11];
    const float* fc_W    = (const float*)d_in[12];
    const float* fc_b    = (const float*)d_in[13];
    const float* W1_W    = (const float*)d_in[14];
    const float* W1_b    = (const float*)d_in[15];
    const float* W2_W    = (const float*)d_in[16];
    const float* W2_b    = (const float*)d_in[17];
    const float* V_W     = (const float*)d_in[18];
    const float* V_b     = (const float*)d_in[19];
    float* out = (float*)d_out;

    float* ws = (float*)d_ws;
    float* hA       = ws;
    float* hB       = hA + (size_t)BATCH * UDIM;
    float* enc_out  = hB + (size_t)BATCH * UDIM;
    float* enc_proj = enc_out + (size_t)BATCH * SLEN * UDIM;
    float* GIH      = enc_proj + (size_t)BATCH * SLEN * UDIM;
    float* GHH      = GIH + (size_t)BATCH * U3;
    float* endBase  = GHH + (size_t)BATCH * U3;
    // Optional big buffer: all encoder ih-gates precomputed
    float* enc_gi   = endBase;
    size_t bigFloats = (size_t)SLEN * BATCH * U3;
    size_t needBig = ((size_t)(endBase - ws) + bigFloats + 256) * sizeof(float);
    bool   big = ws_size >= needBig;
    int*   idx = (int*)(big ? (enc_gi + bigFloats) : endBase);

    float* tmp2 = GIH;  // alias: dead before GIH is written each decode step
    float* gx   = GHH;  // alias: dead before GHH is written each decode step

    init_kernel<<<(BATCH * UDIM + 255) / 256, 256, 0, stream>>>(hA, out, idx);

    // ---- Encoder ----
    if (big) {
        // all ih-gates in one GEMM: [S*B, 3U] = x[S*B,VIN] @ enc_Wih^T
        gemm64<<<dim3(U3 / 64, SLEN * BATCH / 64), 256, 0, stream>>>(
            x, VIND, enc_Wih, VIND, nullptr, enc_gi, U3, VIND);
    }
    float* hc = hA;
    float* hn = hB;
    for (int t = 0; t < SLEN; t++) {
        const float* GIHt;
        if (big) {
            GIHt = enc_gi + (size_t)t * BATCH * U3;
        } else {
            gemm64<<<dim3(U3 / 64, BATCH / 64), 256, 0, stream>>>(
                x + (size_t)t * BATCH * VIND, VIND, enc_Wih, VIND, nullptr, GIH, U3, VIND);
            GIHt = GIH;
        }
        gemm64<<<dim3(U3 / 64, BATCH / 64), 256, 0, stream>>>(
            hc, UDIM, enc_Whh, UDIM, nullptr, GHH, U3, UDIM);
        gru_gates<<<BATCH * UDIM / 4 / 256, 256, 0, stream>>>(
            GIHt, GHH, enc_bih, enc_bhh, hc, hn, enc_out, x_len, t);
        float* tp = hc; hc = hn; hn = tp;
    }

    // ---- enc_proj = enc_out @ W1^T + W1_b ----
    gemm64<<<dim3(UDIM / 64, SLEN * BATCH / 64), 256, 0, stream>>>(
        enc_out, UDIM, W1_W, UDIM, W1_b, enc_proj, UDIM, UDIM);

    // ---- Greedy decode ----
    for (int st = 0; st < TDEC - 1; st++) {
        gemm32<<<dim3(UDIM / 64, BATCH / 32), 256, 0, stream>>>(
            hc, UDIM, W2_W, UDIM, W2_b, tmp2, UDIM, UDIM);
        attn_ctx_kernel<<<BATCH, 256, 0, stream>>>(
            enc_proj, enc_out, tmp2, V_W, V_b, o2h_W, o2h_b, idx, gx);
        gemm64<<<dim3(U3 / 64, BATCH / 64), 256, 0, stream>>>(
            gx, GXW, dec_Wih, GXW, nullptr, GIH, U3, GXW);
        gemm64<<<dim3(U3 / 64, BATCH / 64), 256, 0, stream>>>(
            hc, UDIM, dec_Whh, UDIM, nullptr, GHH, U3, UDIM);
        gru_gates<<<BATCH * UDIM / 4 / 256, 256, 0, stream>>>(
            GIH, GHH, dec_bih, dec_bhh, hc, hn, nullptr, nullptr, 0);
        float* pred = out + (size_t)(1 + st) * BATCH * VOUTD;
        gemm32<<<dim3(VOUTD / 64, BATCH / 32), 256, 0, stream>>>(
            hn, UDIM, fc_W, UDIM, fc_b, pred, VOUTD, UDIM);
        argmax_kernel<<<BATCH, 64, 0, stream>>>(pred, idx);
        float* tp = hc; hc = hn; hn = tp;
    }
}

// Round 5
// 7439.156 us; speedup vs baseline: 2.0393x; 1.6901x over previous
//
#include <hip/hip_runtime.h>
#include <math.h>

#define SLEN 64
#define BATCH 256
#define VIND 128
#define VOUTD 128
#define UDIM 1024
#define EDIM 512
#define TDEC 25
#define GXW 1536
#define U3 3072

typedef __attribute__((ext_vector_type(8))) short short8;
typedef __attribute__((ext_vector_type(4))) float f32x4;

__device__ __forceinline__ float sigm(float x) { return 1.f / (1.f + expf(-x)); }

// round-to-nearest-even fp32 -> bf16
__device__ __forceinline__ short f2bf(float f) {
    unsigned u = __float_as_uint(f);
    u += 0x7FFF + ((u >> 16) & 1);
    return (short)(u >> 16);
}
__device__ __forceinline__ float bf2f(short h) {
    return __uint_as_float(((unsigned)(unsigned short)h) << 16);
}

// fragment-major packed layout for operand X[R][K]:
// chunk(r,k) holds X[r][k..k+8); lane = (r&15) + 16*((k>>3)&3) within 16x32 tile
__device__ __forceinline__ size_t pkChunk(int r, int k, int K) {
    return ((size_t)(r >> 4) * (K >> 5) + (k >> 5)) * 64 + ((r & 15) + 16 * ((k >> 3) & 3));
}

union S8 { short s[8]; short8 v; };

__device__ __forceinline__ void writeSplit8(short* Hi, short* Lo, size_t chunk,
                                            const float* vals) {
    S8 h, l;
#pragma unroll
    for (int j = 0; j < 8; j++) {
        short hb = f2bf(vals[j]);
        h.s[j] = hb;
        l.s[j] = f2bf(vals[j] - bf2f(hb));
    }
    ((short8*)Hi)[chunk] = h.v;
    ((short8*)Lo)[chunk] = l.v;
}

// ---------------------------------------------------------------------------
__global__ void init_kernel(float* __restrict__ h0, short* __restrict__ hpHi,
                            short* __restrict__ hpLo, float* __restrict__ out0,
                            int* __restrict__ idx) {
    int i = blockIdx.x * 256 + threadIdx.x;
    if (i < BATCH * UDIM) { h0[i] = 0.f; hpHi[i] = 0; hpLo[i] = 0; }
    if (i < BATCH * VOUTD) out0[i] = ((i & (VOUTD - 1)) == 0) ? 1.f : 0.f;
    if (i < BATCH) idx[i] = 0;
}

// ---------------------------------------------------------------------------
// split fp32 matrix W[R][K] into packed hi/lo bf16 planes (fragment-major)
// ---------------------------------------------------------------------------
__global__ void pack_split(const float* __restrict__ W, short* __restrict__ Hi,
                           short* __restrict__ Lo, int K, int nChunks) {
    int gid = blockIdx.x * 256 + threadIdx.x;
    if (gid >= nChunks) return;
    int cpr = K >> 3;
    int r = gid / cpr, c = gid - r * cpr, k0 = c * 8;
    const float4* w4 = (const float4*)(W + (size_t)r * K + k0);
    float4 x0 = w4[0], x1 = w4[1];
    float v[8] = {x0.x, x0.y, x0.z, x0.w, x1.x, x1.y, x1.z, x1.w};
    writeSplit8(Hi, Lo, pkChunk(r, k0, K), v);
}

// ---------------------------------------------------------------------------
// Split-bf16 3-pass MFMA GEMM: C[M,N] = A @ W^T (+bias)
// A,W pre-packed fragment-major hi/lo. Block 64x64 (4 waves, wave=32x32).
// Grid: (N/64, M/64). KT = K/32.
// ---------------------------------------------------------------------------
__global__ __launch_bounds__(256) void gemm_sp3(
    const short8* __restrict__ Ahi, const short8* __restrict__ Alo,
    const short8* __restrict__ Whi, const short8* __restrict__ Wlo,
    const float* __restrict__ bias, float* __restrict__ C,
    int KT, int N) {
    int tid = threadIdx.x, lane = tid & 63, wave = tid >> 6;
    int m16 = blockIdx.y * 4 + (wave & 1) * 2;
    int n16 = blockIdx.x * 4 + (wave >> 1) * 2;
    const short8* a0h = Ahi + (size_t)m16 * KT * 64 + lane;
    const short8* a1h = a0h + (size_t)KT * 64;
    const short8* a0l = Alo + (size_t)m16 * KT * 64 + lane;
    const short8* a1l = a0l + (size_t)KT * 64;
    const short8* w0h = Whi + (size_t)n16 * KT * 64 + lane;
    const short8* w1h = w0h + (size_t)KT * 64;
    const short8* w0l = Wlo + (size_t)n16 * KT * 64 + lane;
    const short8* w1l = w0l + (size_t)KT * 64;
    f32x4 acc00 = {0,0,0,0}, acc01 = {0,0,0,0}, acc10 = {0,0,0,0}, acc11 = {0,0,0,0};

    for (int kt = 0; kt < KT; kt++) {
        size_t o = (size_t)kt * 64;
        short8 A0H = a0h[o], A1H = a1h[o], A0L = a0l[o], A1L = a1l[o];
        short8 W0H = w0h[o], W1H = w1h[o], W0L = w0l[o], W1L = w1l[o];
        acc00 = __builtin_amdgcn_mfma_f32_16x16x32_bf16(A0H, W0H, acc00, 0, 0, 0);
        acc01 = __builtin_amdgcn_mfma_f32_16x16x32_bf16(A0H, W1H, acc01, 0, 0, 0);
        acc10 = __builtin_amdgcn_mfma_f32_16x16x32_bf16(A1H, W0H, acc10, 0, 0, 0);
        acc11 = __builtin_amdgcn_mfma_f32_16x16x32_bf16(A1H, W1H, acc11, 0, 0, 0);
        acc00 = __builtin_amdgcn_mfma_f32_16x16x32_bf16(A0H, W0L, acc00, 0, 0, 0);
        acc01 = __builtin_amdgcn_mfma_f32_16x16x32_bf16(A0H, W1L, acc01, 0, 0, 0);
        acc10 = __builtin_amdgcn_mfma_f32_16x16x32_bf16(A1H, W0L, acc10, 0, 0, 0);
        acc11 = __builtin_amdgcn_mfma_f32_16x16x32_bf16(A1H, W1L, acc11, 0, 0, 0);
        acc00 = __builtin_amdgcn_mfma_f32_16x16x32_bf16(A0L, W0H, acc00, 0, 0, 0);
        acc01 = __builtin_amdgcn_mfma_f32_16x16x32_bf16(A0L, W1H, acc01, 0, 0, 0);
        acc10 = __builtin_amdgcn_mfma_f32_16x16x32_bf16(A1L, W0H, acc10, 0, 0, 0);
        acc11 = __builtin_amdgcn_mfma_f32_16x16x32_bf16(A1L, W1H, acc11, 0, 0, 0);
    }
    int rsub = (lane >> 4) * 4, cn = lane & 15;
    float b0 = bias ? bias[(n16 + 0) * 16 + cn] : 0.f;
    float b1 = bias ? bias[(n16 + 1) * 16 + cn] : 0.f;
    int row0 = (m16 + 0) * 16 + rsub;
    int row1 = (m16 + 1) * 16 + rsub;
    int col0 = (n16 + 0) * 16 + cn;
    int col1 = (n16 + 1) * 16 + cn;
#pragma unroll
    for (int r = 0; r < 4; r++) {
        C[(size_t)(row0 + r) * N + col0] = acc00[r] + b0;
        C[(size_t)(row0 + r) * N + col1] = acc01[r] + b1;
        C[(size_t)(row1 + r) * N + col0] = acc10[r] + b0;
        C[(size_t)(row1 + r) * N + col1] = acc11[r] + b1;
    }
}

// ---------------------------------------------------------------------------
// GRU gate combine; writes h fp32 + h split-pack; encoder also writes
// enc_out split-pack (hi+lo == fp32 to ~2^-17: serves enc_proj GEMM AND
// the attention-ctx read path).
// ---------------------------------------------------------------------------
__global__ __launch_bounds__(256) void gru_gates(
    const float* __restrict__ GIH, const float* __restrict__ GHH,
    const float* __restrict__ bih, const float* __restrict__ bhh,
    const float* __restrict__ hin, float* __restrict__ hout,
    short* __restrict__ hpHi, short* __restrict__ hpLo,
    short* __restrict__ eaHi, short* __restrict__ eaLo,
    const int* __restrict__ x_len, int t) {
    int gid = blockIdx.x * 256 + threadIdx.x;
    int b = gid >> 7, u0 = (gid & 127) * 8;
    const float* gi = GIH + (size_t)b * U3;
    const float* gh = GHH + (size_t)b * U3;
    bool enc = (eaHi != nullptr);
    bool msk = enc ? (t < x_len[b]) : true;
    float ho[8], eo[8];
#pragma unroll
    for (int j = 0; j < 8; j++) {
        int u = u0 + j;
        float r = sigm(gi[u] + bih[u] + gh[u] + bhh[u]);
        float z = sigm(gi[UDIM + u] + bih[UDIM + u] + gh[UDIM + u] + bhh[UDIM + u]);
        float n = tanhf(gi[2 * UDIM + u] + bih[2 * UDIM + u] +
                        r * (gh[2 * UDIM + u] + bhh[2 * UDIM + u]));
        float hp = hin[(size_t)b * UDIM + u];
        float hv = (1.f - z) * n + z * hp;
        ho[j] = msk ? hv : hp;
        eo[j] = msk ? hv : 0.f;
    }
#pragma unroll
    for (int j = 0; j < 8; j++) hout[(size_t)b * UDIM + u0 + j] = ho[j];
    writeSplit8(hpHi, hpLo, pkChunk(b, u0, UDIM), ho);
    if (enc) {
        writeSplit8(eaHi, eaLo, pkChunk(b * SLEN + t, u0, UDIM), eo);
    }
}

// ---------------------------------------------------------------------------
// Attention scores + softmax + context + emb gather -> gx split-pack [B,1536]
// enc_proj read fp32; enc_out reconstructed from split hi/lo (== fp32).
// ---------------------------------------------------------------------------
__global__ __launch_bounds__(256) void attn_ctx(
    const float* __restrict__ encProj,
    const short* __restrict__ eaHi, const short* __restrict__ eaLo,
    const float* __restrict__ tmp2, const float* __restrict__ V_W,
    const float* __restrict__ V_b,
    const float* __restrict__ o2h_W, const float* __restrict__ o2h_b,
    const int* __restrict__ idx, short* __restrict__ gxHi, short* __restrict__ gxLo) {
    int b = blockIdx.x;
    int tid = threadIdx.x, lane = tid & 63, wave = tid >> 6;
    __shared__ float s_t2[UDIM];
    __shared__ float s_v[UDIM];
    __shared__ float s_attn[SLEN];
    for (int u = tid; u < UDIM; u += 256) {
        s_t2[u] = tmp2[(size_t)b * UDIM + u];
        s_v[u] = V_W[u];
    }
    __syncthreads();
    for (int s = wave; s < SLEN; s += 4) {
        const float4* ep4 = (const float4*)(encProj + ((size_t)b * SLEN + s) * UDIM);
        float p = 0.f;
        for (int u4 = lane; u4 < UDIM / 4; u4 += 64) {
            float4 e = ep4[u4];
            int u = 4 * u4;
            p += tanhf(e.x + s_t2[u]) * s_v[u] +
                 tanhf(e.y + s_t2[u + 1]) * s_v[u + 1] +
                 tanhf(e.z + s_t2[u + 2]) * s_v[u + 2] +
                 tanhf(e.w + s_t2[u + 3]) * s_v[u + 3];
        }
#pragma unroll
        for (int off = 32; off > 0; off >>= 1) p += __shfl_xor(p, off);
        if (lane == 0) s_attn[s] = p + V_b[0];
    }
    __syncthreads();
    if (tid < 64) {
        float v = s_attn[tid];
        float mx = v;
#pragma unroll
        for (int off = 32; off > 0; off >>= 1) mx = fmaxf(mx, __shfl_xor(mx, off));
        float e = expf(v - mx);
        float sum = e;
#pragma unroll
        for (int off = 32; off > 0; off >>= 1) sum += __shfl_xor(sum, off);
        s_attn[tid] = e / sum;
    }
    __syncthreads();
    if (tid < 128) {
        int u0 = tid * 8;
        float a[8] = {0, 0, 0, 0, 0, 0, 0, 0};
        const short8* hi8 = (const short8*)eaHi;
        const short8* lo8 = (const short8*)eaLo;
        int lanePart = 16 * ((u0 >> 3) & 3);
        int colPart = u0 >> 5;
        for (int s = 0; s < SLEN; s++) {
            int r = b * SLEN + s;
            size_t ch = ((size_t)(r >> 4) * (UDIM >> 5) + colPart) * 64 + (r & 15) + lanePart;
            S8 h, l;
            h.v = hi8[ch];
            l.v = lo8[ch];
            float w = s_attn[s];
#pragma unroll
            for (int j = 0; j < 8; j++) a[j] += w * (bf2f(h.s[j]) + bf2f(l.s[j]));
        }
        writeSplit8(gxHi, gxLo, pkChunk(b, u0, GXW), a);
    } else if (tid < 192) {
        int e0 = (tid - 128) * 8;
        int ib = idx[b];
        float a[8];
#pragma unroll
        for (int j = 0; j < 8; j++)
            a[j] = o2h_W[(size_t)(e0 + j) * VOUTD + ib] + o2h_b[e0 + j];
        writeSplit8(gxHi, gxLo, pkChunk(b, UDIM + e0, GXW), a);
    }
}

// ---------------------------------------------------------------------------
__global__ void argmax_kernel(const float* __restrict__ pred, int* __restrict__ idx) {
    int b = blockIdx.x;
    int lane = threadIdx.x;
    float v0 = pred[(size_t)b * VOUTD + lane];
    float v1 = pred[(size_t)b * VOUTD + 64 + lane];
    float v; int i;
    if (v1 > v0) { v = v1; i = lane + 64; } else { v = v0; i = lane; }
#pragma unroll
    for (int off = 32; off > 0; off >>= 1) {
        float ov = __shfl_xor(v, off);
        int oi = __shfl_xor(i, off);
        if (ov > v || (ov == v && oi < i)) { v = ov; i = oi; }
    }
    if (lane == 0) idx[b] = i;
}

// ---------------------------------------------------------------------------
extern "C" void kernel_launch(void* const* d_in, const int* in_sizes, int n_in,
                              void* d_out, int out_size, void* d_ws, size_t ws_size,
                              hipStream_t stream) {
    const float* x       = (const float*)d_in[0];
    const int*   x_len   = (const int*)d_in[1];
    const float* enc_Wih = (const float*)d_in[2];
    const float* enc_Whh = (const float*)d_in[3];
    const float* enc_bih = (const float*)d_in[4];
    const float* enc_bhh = (const float*)d_in[5];
    const float* dec_Wih = (const float*)d_in[6];
    const float* dec_Whh = (const float*)d_in[7];
    const float* dec_bih = (const float*)d_in[8];
    const float* dec_bhh = (const float*)d_in[9];
    const float* o2h_W   = (const float*)d_in[10];
    const float* o2h_b   = (const float*)d_in[11];
    const float* fc_W    = (const float*)d_in[12];
    const float* fc_b    = (const float*)d_in[13];
    const float* W1_W    = (const float*)d_in[14];
    const float* W1_b    = (const float*)d_in[15];
    const float* W2_W    = (const float*)d_in[16];
    const float* W2_b    = (const float*)d_in[17];
    const float* V_W     = (const float*)d_in[18];
    const float* V_b     = (const float*)d_in[19];
    float* out = (float*)d_out;

    char* p = (char*)d_ws;
    auto alloc = [&](size_t bytes) -> char* {
        char* q = p;
        p += (bytes + 255) & ~(size_t)255;
        return q;
    };
    // Base footprint ~199.5 MB — matches round-3's known-good size.
    float* hA   = (float*)alloc((size_t)BATCH * UDIM * 4);
    float* hB   = (float*)alloc((size_t)BATCH * UDIM * 4);
    float* GIH  = (float*)alloc((size_t)BATCH * U3 * 4);
    float* GHH  = (float*)alloc((size_t)BATCH * U3 * 4);
    float* tmp2 = (float*)alloc((size_t)BATCH * UDIM * 4);
    short* hpHi = (short*)alloc((size_t)BATCH * UDIM * 2);
    short* hpLo = (short*)alloc((size_t)BATCH * UDIM * 2);
    short* gxHi = (short*)alloc((size_t)BATCH * GXW * 2);
    short* gxLo = (short*)alloc((size_t)BATCH * GXW * 2);
    short* encAHi   = (short*)alloc((size_t)BATCH * SLEN * UDIM * 2);
    short* encALo   = (short*)alloc((size_t)BATCH * SLEN * UDIM * 2);
    float* encProjF = (float*)alloc((size_t)BATCH * SLEN * UDIM * 4);
    short* eWihHi = (short*)alloc((size_t)U3 * VIND * 2);
    short* eWihLo = (short*)alloc((size_t)U3 * VIND * 2);
    short* eWhhHi = (short*)alloc((size_t)U3 * UDIM * 2);
    short* eWhhLo = (short*)alloc((size_t)U3 * UDIM * 2);
    short* dWihHi = (short*)alloc((size_t)U3 * GXW * 2);
    short* dWihLo = (short*)alloc((size_t)U3 * GXW * 2);
    short* dWhhHi = (short*)alloc((size_t)U3 * UDIM * 2);
    short* dWhhLo = (short*)alloc((size_t)U3 * UDIM * 2);
    short* w1Hi = (short*)alloc((size_t)UDIM * UDIM * 2);
    short* w1Lo = (short*)alloc((size_t)UDIM * UDIM * 2);
    short* w2Hi = (short*)alloc((size_t)UDIM * UDIM * 2);
    short* w2Lo = (short*)alloc((size_t)UDIM * UDIM * 2);
    short* fcHi = (short*)alloc((size_t)VOUTD * UDIM * 2);
    short* fcLo = (short*)alloc((size_t)VOUTD * UDIM * 2);
    short* xHi  = (short*)alloc((size_t)SLEN * BATCH * VIND * 2);
    short* xLo  = (short*)alloc((size_t)SLEN * BATCH * VIND * 2);
    int*   idx  = (int*)alloc(BATCH * 4);
    size_t used = (size_t)(p - (char*)d_ws);
    size_t giBytes = (size_t)SLEN * BATCH * U3 * 4;
    bool big = (ws_size >= used + giBytes + 1024);
    float* enc_gi = big ? (float*)alloc(giBytes) : nullptr;

    init_kernel<<<(BATCH * UDIM + 255) / 256, 256, 0, stream>>>(hA, hpHi, hpLo, out, idx);

    // ---- pack weights (constant per call, rebuilt every call: graph-safe) ----
    auto packW = [&](const float* W, short* Hi, short* Lo, int R, int K) {
        int chunks = R * K / 8;
        pack_split<<<(chunks + 255) / 256, 256, 0, stream>>>(W, Hi, Lo, K, chunks);
    };
    packW(enc_Wih, eWihHi, eWihLo, U3, VIND);
    packW(enc_Whh, eWhhHi, eWhhLo, U3, UDIM);
    packW(dec_Wih, dWihHi, dWihLo, U3, GXW);
    packW(dec_Whh, dWhhHi, dWhhLo, U3, UDIM);
    packW(W1_W, w1Hi, w1Lo, UDIM, UDIM);
    packW(W2_W, w2Hi, w2Lo, UDIM, UDIM);
    packW(fc_W, fcHi, fcLo, VOUTD, UDIM);
    packW(x, xHi, xLo, SLEN * BATCH, VIND);  // x rows r = t*256 + b

    // ---- encoder ih-gates (one big GEMM if workspace allows) ----
    if (big) {
        gemm_sp3<<<dim3(U3 / 64, SLEN * BATCH / 64), 256, 0, stream>>>(
            (const short8*)xHi, (const short8*)xLo,
            (const short8*)eWihHi, (const short8*)eWihLo,
            nullptr, enc_gi, VIND / 32, U3);
    }

    // ---- encoder: 64 steps ----
    float* hc = hA;
    float* hn = hB;
    for (int t = 0; t < SLEN; t++) {
        const float* GIHt;
        if (big) {
            GIHt = enc_gi + (size_t)t * BATCH * U3;
        } else {
            gemm_sp3<<<dim3(U3 / 64, BATCH / 64), 256, 0, stream>>>(
                (const short8*)xHi + (size_t)t * 16 * (VIND / 32) * 64,
                (const short8*)xLo + (size_t)t * 16 * (VIND / 32) * 64,
                (const short8*)eWihHi, (const short8*)eWihLo,
                nullptr, GIH, VIND / 32, U3);
            GIHt = GIH;
        }
        gemm_sp3<<<dim3(U3 / 64, BATCH / 64), 256, 0, stream>>>(
            (const short8*)hpHi, (const short8*)hpLo,
            (const short8*)eWhhHi, (const short8*)eWhhLo,
            nullptr, GHH, UDIM / 32, U3);
        gru_gates<<<BATCH * UDIM / 8 / 256, 256, 0, stream>>>(
            GIHt, GHH, enc_bih, enc_bhh, hc, hn, hpHi, hpLo,
            encAHi, encALo, x_len, t);
        float* tp = hc; hc = hn; hn = tp;
    }

    // ---- enc_proj = enc_out @ W1^T + W1_b  (fp32 out, precision-critical) ----
    gemm_sp3<<<dim3(UDIM / 64, SLEN * BATCH / 64), 256, 0, stream>>>(
        (const short8*)encAHi, (const short8*)encALo,
        (const short8*)w1Hi, (const short8*)w1Lo,
        W1_b, encProjF, UDIM / 32, UDIM);

    // ---- greedy decode: 24 steps ----
    for (int st = 0; st < TDEC - 1; st++) {
        gemm_sp3<<<dim3(UDIM / 64, BATCH / 64), 256, 0, stream>>>(
            (const short8*)hpHi, (const short8*)hpLo,
            (const short8*)w2Hi, (const short8*)w2Lo,
            W2_b, tmp2, UDIM / 32, UDIM);
        attn_ctx<<<BATCH, 256, 0, stream>>>(
            encProjF, encAHi, encALo, tmp2, V_W, V_b, o2h_W, o2h_b, idx, gxHi, gxLo);
        gemm_sp3<<<dim3(U3 / 64, BATCH / 64), 256, 0, stream>>>(
            (const short8*)gxHi, (const short8*)gxLo,
            (const short8*)dWihHi, (const short8*)dWihLo,
            nullptr, GIH, GXW / 32, U3);
        gemm_sp3<<<dim3(U3 / 64, BATCH / 64), 256, 0, stream>>>(
            (const short8*)hpHi, (const short8*)hpLo,
            (const short8*)dWhhHi, (const short8*)dWhhLo,
            nullptr, GHH, UDIM / 32, U3);
        gru_gates<<<BATCH * UDIM / 8 / 256, 256, 0, stream>>>(
            GIH, GHH, dec_bih, dec_bhh, hc, hn, hpHi, hpLo,
            nullptr, nullptr, nullptr, 0);
        float* pred = out + (size_t)(1 + st) * BATCH * VOUTD;
        gemm_sp3<<<dim3(VOUTD / 64, BATCH / 64), 256, 0, stream>>>(
            (const short8*)hpHi, (const short8*)hpLo,
            (const short8*)fcHi, (const short8*)fcLo,
            fc_b, pred, UDIM / 32, VOUTD);
        argmax_kernel<<<BATCH, 64, 0, stream>>>(pred, idx);
        float* tp = hc; hc = hn; hn = tp;
    }
}